// Round 8
// baseline (150.808 us; speedup 1.0000x reference)
//
#include <hip/hip_runtime.h>

// B=4, H=W=32, C=256. 8 tasks (sample x orientation), grid L=992 each.
// Pipeline (6 dispatches):
//   k_stage:    Mh=f16(a*b), ABt (transposed f16 a|b), per-pixel sq norms
//   k_gram:     S = Mh Mh^T (MFMA f16 -> B0), SYMMETRIC: 136 upper-tri tiles,
//               mirror written via LDS transpose; u==0 also computes inv
//   k_softmax9: G = 9-pt band(S) -> MAX-FREE softmax -> Ph (B0->B1),
//               wave-per-row (barrier-free; |logit|<=10 so no max needed)
//   k_band9p:   Wh = 9-pt band(Ph) (B1->B0), wave-per-row
//   k_recon:    Y(f16) = Wh @ ABt^T (MFMA f16), 64x64 tiles
//   k_combine:  seam average -> out
// Stencils: unconditional 4B-aligned vector loads + mask-as-select (R5 win).

typedef _Float16 half8 __attribute__((ext_vector_type(8)));
typedef _Float16 half8u __attribute__((ext_vector_type(8), aligned(4)));
typedef _Float16 half4h __attribute__((ext_vector_type(4)));
typedef _Float16 half4u __attribute__((ext_vector_type(4), aligned(8)));
typedef float floatx4 __attribute__((ext_vector_type(4)));

constexpr int NL = 992, NC = 256, NC2 = 512;
constexpr int NLL = NL * NL;
// float-granular per-task offsets. B0/B1 last: +-66KB stencil over/under-
// reads stay inside d_ws (ws is 256MB, we use 47.8MB).
constexpr int OFF_ABT = 0;                      // f16 [512][992]
constexpr int OFF_MH  = OFF_ABT + NL * NC2 / 2; // f16 [992][256]
constexpr int OFF_SA  = OFF_MH + NL * NC / 2;
constexpr int OFF_SB  = OFF_SA + 1024;
constexpr int OFF_INV = OFF_SA + 2048;          // 1024 slots
constexpr int OFF_Y   = OFF_SA + 3072;          // f16 [992][512]
constexpr int OFF_B0  = OFF_Y + NL * NC2 / 2;   // f16 LxL: S, later Wh
constexpr int OFF_B1  = OFF_B0 + NLL / 2;       // f16 LxL: Ph
constexpr int TSTRIDE = OFF_B1 + NLL / 2;       // 1,495,040 f -> 47.8 MB

__device__ __forceinline__ void gload16(const void* g, void* l) {
    __builtin_amdgcn_global_load_lds(
        (const __attribute__((address_space(1))) unsigned int*)g,
        (__attribute__((address_space(3))) unsigned int*)(unsigned long)(uintptr_t)l,
        16, 0, 0);
}

// ------- K1: one x-pass -> Mh, ABt (both halves), per-pixel sq norms -------
__global__ __launch_bounds__(256) void k_stage(const float* __restrict__ x,
                                               float* __restrict__ ws) {
    const int t = blockIdx.x & 7;
    const int l0 = (blockIdx.x >> 3) * 32;   // 31 l-blocks
    const int s = t >> 1, o = t & 1;
    float* wst = ws + (size_t)t * TSTRIDE;
    _Float16* __restrict__ ABt = (_Float16*)(wst + OFF_ABT);
    _Float16* __restrict__ Mh = (_Float16*)(wst + OFF_MH);
    __shared__ float Ta[32 * 33], Tb[32 * 33];
    const int tid = threadIdx.x;
    const int li = tid >> 3, cq = tid & 7;
    const int l = l0 + li;
    int aoff, boff;
    if (o == 0) {  // lr grid (31,32): a=x[s,lh,lw], b=x[s,lh+1,lw]
        const int lh = l >> 5, lw = l & 31;
        aoff = ((s * 32 + lh) * 32 + lw) * NC;
        boff = aoff + 32 * NC;
    } else {       // tb grid (32,31): a=x[s,lh,lw+1], b=x[s,lh,lw]
        const int lh = l / 31, lw = l - lh * 31;
        boff = ((s * 32 + lh) * 32 + lw) * NC;
        aoff = boff + NC;
    }
    float sa = 0.0f, sb = 0.0f;
    for (int cc = 0; cc < 8; ++cc) {
        const int c0 = cc * 32;
        const float4 a4 = *(const float4*)&x[aoff + c0 + cq * 4];
        const float4 b4 = *(const float4*)&x[boff + c0 + cq * 4];
        half4h m;
        m[0] = (_Float16)(a4.x * b4.x); m[1] = (_Float16)(a4.y * b4.y);
        m[2] = (_Float16)(a4.z * b4.z); m[3] = (_Float16)(a4.w * b4.w);
        *(half4u*)&Mh[l * NC + c0 + cq * 4] = m;
        sa += a4.x * a4.x + a4.y * a4.y + a4.z * a4.z + a4.w * a4.w;
        sb += b4.x * b4.x + b4.y * b4.y + b4.z * b4.z + b4.w * b4.w;
        __syncthreads();   // guard previous iteration's LDS reads
        Ta[(cq * 4 + 0) * 33 + li] = a4.x; Tb[(cq * 4 + 0) * 33 + li] = b4.x;
        Ta[(cq * 4 + 1) * 33 + li] = a4.y; Tb[(cq * 4 + 1) * 33 + li] = b4.y;
        Ta[(cq * 4 + 2) * 33 + li] = a4.z; Tb[(cq * 4 + 2) * 33 + li] = b4.z;
        Ta[(cq * 4 + 3) * 33 + li] = a4.w; Tb[(cq * 4 + 3) * 33 + li] = b4.w;
        __syncthreads();
        const int ci = li, lq = cq;
        half4h ha, hb;
#pragma unroll
        for (int j = 0; j < 4; ++j) {
            ha[j] = (_Float16)Ta[ci * 33 + lq * 4 + j];
            hb[j] = (_Float16)Tb[ci * 33 + lq * 4 + j];
        }
        *(half4u*)&ABt[(c0 + ci) * NL + l0 + lq * 4] = ha;
        *(half4u*)&ABt[(NC + c0 + ci) * NL + l0 + lq * 4] = hb;
    }
#pragma unroll
    for (int off = 4; off > 0; off >>= 1) {
        sa += __shfl_down(sa, off, 8);
        sb += __shfl_down(sb, off, 8);
    }
    if (cq == 0) {
        wst[OFF_SA + l] = sa;
        wst[OFF_SB + l] = sb;
    }
}

// --- K2: S = Mh Mh^T, symmetric upper-tri 64x64 tiles + LDS-bounced mirror ---
__global__ __launch_bounds__(256) void k_gram(float* __restrict__ ws) {
    const int t = blockIdx.x & 7;
    int uu = blockIdx.x >> 3;         // 0..135 upper-tri pair index
    int ti = 0;
    while (uu >= 16 - ti) { uu -= 16 - ti; ++ti; }
    const int tj = ti + uu;
    const int i0 = ti * 64, j0 = tj * 64;
    float* wst = ws + (size_t)t * TSTRIDE;
    const _Float16* __restrict__ M = (const _Float16*)(wst + OFF_MH);
    _Float16* __restrict__ S = (_Float16*)(wst + OFF_B0);
    const int tid = threadIdx.x;

    if (blockIdx.x >> 3 == 0) {  // fused inv
        const int o = t & 1;
        const int Hp = o ? 32 : 31, Wp = o ? 31 : 32;
#pragma unroll
        for (int q = 0; q < 4; ++q) {
            const int l = tid + q * 256;
            if (l < NL) {
                const int h = l / Wp, w = l - h * Wp;
                float na2 = 0.0f, nb2 = 0.0f;
#pragma unroll
                for (int dh = -1; dh <= 1; ++dh)
#pragma unroll
                    for (int dw = -1; dw <= 1; ++dw) {
                        const int hh = h + dh, ww = w + dw;
                        if ((unsigned)hh < (unsigned)Hp && (unsigned)ww < (unsigned)Wp) {
                            const int ll = hh * Wp + ww;
                            na2 += wst[OFF_SA + ll];
                            nb2 += wst[OFF_SB + ll];
                        }
                    }
                const float na = fmaxf(sqrtf(na2), 1e-4f);
                const float nb = fmaxf(sqrtf(nb2), 1e-4f);
                wst[OFF_INV + l] = 1.0f / (na * nb);
            }
        }
    }

    __shared__ __align__(16) _Float16 As[64 * 64];
    __shared__ __align__(16) _Float16 Bs[64 * 64];
    __shared__ __align__(16) _Float16 Ts[64 * 72];   // pad 72: conflict-free transpose
    const int wave = tid >> 6, lane = tid & 63;
    const int wm = wave & 1, wn = wave >> 1;
    const int l15 = lane & 15, quad = lane >> 4;
    floatx4 acc[2][2] = {};
    for (int k0 = 0; k0 < NC; k0 += 64) {   // 4 iters
        __syncthreads();
#pragma unroll
        for (int rr = 0; rr < 2; ++rr) {
            const int slot = tid + rr * 256;
            const int row = slot >> 3, cg = (slot & 7) * 8;
            if (i0 + row < NL) gload16(&M[(i0 + row) * NC + k0 + cg], &As[row * 64 + cg]);
            if (j0 + row < NL) gload16(&M[(j0 + row) * NC + k0 + cg], &Bs[row * 64 + cg]);
        }
        __syncthreads();
#pragma unroll
        for (int kk = 0; kk < 2; ++kk) {
            half8 a[2], b[2];
#pragma unroll
            for (int mt = 0; mt < 2; ++mt) a[mt] = *(const half8*)&As[(wm * 32 + mt * 16 + l15) * 64 + kk * 32 + quad * 8];
#pragma unroll
            for (int nt = 0; nt < 2; ++nt) b[nt] = *(const half8*)&Bs[(wn * 32 + nt * 16 + l15) * 64 + kk * 32 + quad * 8];
#pragma unroll
            for (int mt = 0; mt < 2; ++mt)
#pragma unroll
                for (int nt = 0; nt < 2; ++nt)
                    acc[mt][nt] = __builtin_amdgcn_mfma_f32_16x16x32_f16(a[mt], b[nt], acc[mt][nt], 0, 0, 0);
        }
    }
    // dump acc tile to LDS (f16), then vector-write straight + mirror
    __syncthreads();
#pragma unroll
    for (int mt = 0; mt < 2; ++mt)
#pragma unroll
        for (int nt = 0; nt < 2; ++nt)
#pragma unroll
            for (int r = 0; r < 4; ++r) {
                const int row = wm * 32 + mt * 16 + quad * 4 + r;
                const int col = wn * 32 + nt * 16 + l15;
                Ts[row * 72 + col] = (_Float16)acc[mt][nt][r];
            }
    __syncthreads();
    const int trow = tid >> 3, tcg = (tid & 7) * 8;
#pragma unroll
    for (int rr = 0; rr < 2; ++rr) {
        const int row = trow + rr * 32;
        if (i0 + row < NL && j0 + tcg < NL) {
            const half8 v = *(const half8*)&Ts[row * 72 + tcg];
            *(half8*)&S[(i0 + row) * NL + j0 + tcg] = v;
        }
    }
    if (i0 != j0) {
#pragma unroll
        for (int rr = 0; rr < 2; ++rr) {
            const int row2 = trow + rr * 32;     // mirror row = orig col
            if (j0 + row2 < NL && i0 + tcg < NL) {
                half8 v;
#pragma unroll
                for (int k = 0; k < 8; ++k) v[k] = Ts[(tcg + k) * 72 + row2];
                *(half8*)&S[(j0 + row2) * NL + i0 + tcg] = v;
            }
        }
    }
}

// --- K3: G = 9-pt band(S) -> MAX-FREE softmax -> Ph, wave-per-row, B0->B1 ---
// |logit| = |10*G*inv1*inv2| <= 10 (Cauchy-Schwarz), so exp() is fp32-safe
// without max subtraction; row sum <= 992*e^10 << fp32 max.
template<int WP, int HP>
__device__ __forceinline__ void softmax9_body(float* __restrict__ wst,
                                              const int l1, const int lane) {
    const _Float16* __restrict__ S = (const _Float16*)(wst + OFF_B0);
    const float* __restrict__ inv = wst + OFF_INV;
    _Float16* __restrict__ Ph = (_Float16*)(wst + OFF_B1);
    const int h1 = l1 / WP, w1 = l1 % WP;
    const float inv1 = inv[l1] * 10.0f;
    float e[16];
    float sum = 0.0f;
#pragma unroll
    for (int jj = 0; jj < 4; ++jj) {
        const bool act = (jj < 3) | (lane < 56);   // 992 = 3*256 + 56*4
        const int c0 = jj * 256 + lane * 4;
        int hc[4], wc[4];
#pragma unroll
        for (int j = 0; j < 4; ++j) { hc[j] = (c0 + j) / WP; wc[j] = (c0 + j) % WP; }
        float g[4] = {0.f, 0.f, 0.f, 0.f};
        const _Float16* base = S + l1 * NL + c0;
#pragma unroll
        for (int dh = -1; dh <= 1; ++dh) {
            const bool oh1 = (unsigned)(h1 + dh) < (unsigned)HP;
#pragma unroll
            for (int dw = -1; dw <= 1; ++dw) {
                const int sh = dh * WP + dw;     // compile-time after unroll
                const int par = sh & 1;
                const bool ok1 = oh1 && (unsigned)(w1 + dw) < (unsigned)WP;
                const half8u v = *(const half8u*)(base + sh * (NL + 1) - par);
#pragma unroll
                for (int j = 0; j < 4; ++j) {
                    const bool ok = ok1 && (unsigned)(hc[j] + dh) < (unsigned)HP &&
                                           (unsigned)(wc[j] + dw) < (unsigned)WP;
                    if (ok) g[j] += (float)v[j + par];
                }
            }
        }
#pragma unroll
        for (int j = 0; j < 4; ++j) {
            const float ee = act ? __expf(g[j] * inv1 * inv[c0 + j]) : 0.0f;
            e[jj * 4 + j] = ee;
            sum += ee;
        }
    }
#pragma unroll
    for (int off = 32; off > 0; off >>= 1) sum += __shfl_down(sum, off);
    const float rs = 1.0f / __shfl(sum, 0);
#pragma unroll
    for (int jj = 0; jj < 4; ++jj) {
        if ((jj < 3) | (lane < 56)) {
            const int c0 = jj * 256 + lane * 4;
            half4h o;
#pragma unroll
            for (int j = 0; j < 4; ++j) o[j] = (_Float16)(e[jj * 4 + j] * rs);
            *(half4u*)(Ph + l1 * NL + c0) = o;
        }
    }
}

__global__ __launch_bounds__(256) void k_softmax9(float* __restrict__ ws) {
    const int t = blockIdx.x & 7;
    const int rb = blockIdx.x >> 3;          // 0..247
    const int wave = threadIdx.x >> 6, lane = threadIdx.x & 63;
    const int l1 = rb * 4 + wave;            // 992 rows exact
    float* wst = ws + (size_t)t * TSTRIDE;
    if (t & 1) softmax9_body<31, 32>(wst, l1, lane);
    else       softmax9_body<32, 31>(wst, l1, lane);
}

// ------- K4: Wh = 9-pt band(Ph), wave-per-row, B1 -> B0 -------
template<int WP, int HP>
__device__ __forceinline__ void band9p_body(float* __restrict__ wst,
                                            const int m, const int lane) {
    const _Float16* __restrict__ P = (const _Float16*)(wst + OFF_B1);
    _Float16* __restrict__ W = (_Float16*)(wst + OFF_B0);
    const int hm = m / WP, wm = m % WP;
#pragma unroll
    for (int jj = 0; jj < 4; ++jj) {
        const bool act = (jj < 3) | (lane < 56);
        if (!act) continue;
        const int c0 = jj * 256 + lane * 4;
        int hc[4], wc[4];
#pragma unroll
        for (int j = 0; j < 4; ++j) { hc[j] = (c0 + j) / WP; wc[j] = (c0 + j) % WP; }
        float acc[4] = {0.f, 0.f, 0.f, 0.f};
        const _Float16* base = P + m * NL + c0;
#pragma unroll
        for (int dh = -1; dh <= 1; ++dh) {
            const bool oh1 = (unsigned)(hm + dh) < (unsigned)HP;
#pragma unroll
            for (int dw = -1; dw <= 1; ++dw) {
                const int sh = dh * WP + dw;
                const int par = sh & 1;
                const bool ok1 = oh1 && (unsigned)(wm + dw) < (unsigned)WP;
                const half8u v = *(const half8u*)(base + sh * (NL + 1) - par);
#pragma unroll
                for (int j = 0; j < 4; ++j) {
                    const bool ok = ok1 && (unsigned)(hc[j] + dh) < (unsigned)HP &&
                                           (unsigned)(wc[j] + dw) < (unsigned)WP;
                    if (ok) acc[j] += (float)v[j + par];
                }
            }
        }
        half4h o;
#pragma unroll
        for (int j = 0; j < 4; ++j) o[j] = (_Float16)acc[j];
        *(half4u*)(W + m * NL + c0) = o;
    }
}

__global__ __launch_bounds__(256) void k_band9p(float* __restrict__ ws) {
    const int t = blockIdx.x & 7;
    const int rb = blockIdx.x >> 3;
    const int wave = threadIdx.x >> 6, lane = threadIdx.x & 63;
    const int m = rb * 4 + wave;
    float* wst = ws + (size_t)t * TSTRIDE;
    if (t & 1) band9p_body<31, 32>(wst, m, lane);
    else       band9p_body<32, 31>(wst, m, lane);
}

// -------- K5: Y(f16) = Wh @ ABt^T, 64x64 tile, BK=32, 31 exact iters -------
__global__ __launch_bounds__(256) void k_recon(float* __restrict__ ws) {
    const int t = blockIdx.x & 7;
    const int u = blockIdx.x >> 3;    // 0..127 = 16 iy x 8 jx
    const int i0 = (u >> 3) * 64, j0 = (u & 7) * 64;
    float* wst = ws + (size_t)t * TSTRIDE;
    const _Float16* __restrict__ Wm = (const _Float16*)(wst + OFF_B0);
    const _Float16* __restrict__ ABt = (const _Float16*)(wst + OFF_ABT);
    _Float16* __restrict__ Y = (_Float16*)(wst + OFF_Y);
    __shared__ __align__(16) _Float16 As[64 * 32];
    __shared__ __align__(16) _Float16 Bs[64 * 32];
    const int tid = threadIdx.x;
    const int wave = tid >> 6, lane = tid & 63;
    const int wm = wave & 1, wn = wave >> 1;
    const int l15 = lane & 15, quad = lane >> 4;
    floatx4 acc[2][2] = {};
    const int row = tid >> 2, cg = (tid & 3) * 8;
    for (int k0 = 0; k0 < NL; k0 += 32) {   // 31 exact iterations
        __syncthreads();
        if (i0 + row < NL) gload16(&Wm[(i0 + row) * NL + k0 + cg], &As[row * 32 + cg]);
        gload16(&ABt[(j0 + row) * NL + k0 + cg], &Bs[row * 32 + cg]);
        __syncthreads();
        half8 a[2], b[2];
#pragma unroll
        for (int mt = 0; mt < 2; ++mt) a[mt] = *(const half8*)&As[(wm * 32 + mt * 16 + l15) * 32 + quad * 8];
#pragma unroll
        for (int nt = 0; nt < 2; ++nt) b[nt] = *(const half8*)&Bs[(wn * 32 + nt * 16 + l15) * 32 + quad * 8];
#pragma unroll
        for (int mt = 0; mt < 2; ++mt)
#pragma unroll
            for (int nt = 0; nt < 2; ++nt)
                acc[mt][nt] = __builtin_amdgcn_mfma_f32_16x16x32_f16(a[mt], b[nt], acc[mt][nt], 0, 0, 0);
    }
#pragma unroll
    for (int mt = 0; mt < 2; ++mt)
#pragma unroll
        for (int nt = 0; nt < 2; ++nt)
#pragma unroll
            for (int r = 0; r < 4; ++r) {
                const int rw = i0 + wm * 32 + mt * 16 + quad * 4 + r;
                const int col = j0 + wn * 32 + nt * 16 + l15;
                if (rw < NL) Y[rw * NC2 + col] = (_Float16)acc[mt][nt][r];
            }
}

// ---------------- K6: seam combine -> out ----------------
__global__ __launch_bounds__(256) void k_combine(float* __restrict__ out,
                                                 const float* __restrict__ ws) {
    const int idx = blockIdx.x;          // s*1024 + h*32 + w
    const int s = idx >> 10;
    const int hw = idx & 1023;
    const int h = hw >> 5, w = hw & 31;
    const int c = threadIdx.x;
    const _Float16* Ylr = (const _Float16*)(ws + (size_t)(2 * s) * TSTRIDE + OFF_Y);
    const _Float16* Ytb = (const _Float16*)(ws + (size_t)(2 * s + 1) * TSTRIDE + OFF_Y);
    float v = 0.0f;
    if (h < 31) v += (float)Ylr[(h * 32 + w) * NC2 + NC + c] * (h == 0 ? 1.0f : 0.5f);
    if (h >= 1) v += (float)Ylr[((h - 1) * 32 + w) * NC2 + c] * (h == 31 ? 1.0f : 0.5f);
    if (w < 31) v += (float)Ytb[(h * 31 + w) * NC2 + c] * (w == 0 ? 1.0f : 0.5f);
    if (w >= 1) v += (float)Ytb[(h * 31 + (w - 1)) * NC2 + NC + c] * (w == 31 ? 1.0f : 0.5f);
    out[(size_t)idx * NC + c] = v * 0.5f;
}

extern "C" void kernel_launch(void* const* d_in, const int* in_sizes, int n_in,
                              void* d_out, int out_size, void* d_ws, size_t ws_size,
                              hipStream_t stream) {
    const float* x = (const float*)d_in[0];
    float* out = (float*)d_out;
    float* ws = (float*)d_ws;    // 8*TSTRIDE*4 = 47.8 MB used

    hipLaunchKernelGGL(k_stage,    dim3(8 * 31),  dim3(256), 0, stream, x, ws);
    hipLaunchKernelGGL(k_gram,     dim3(8 * 136), dim3(256), 0, stream, ws);
    hipLaunchKernelGGL(k_softmax9, dim3(8 * 248), dim3(256), 0, stream, ws);
    hipLaunchKernelGGL(k_band9p,   dim3(8 * 248), dim3(256), 0, stream, ws);
    hipLaunchKernelGGL(k_recon,    dim3(8 * 128), dim3(256), 0, stream, ws);
    hipLaunchKernelGGL(k_combine,  dim3(4096),    dim3(256), 0, stream, out, ws);
}

// Round 9
// 144.391 us; speedup vs baseline: 1.0444x; 1.0444x over previous
//
#include <hip/hip_runtime.h>

// B=4, H=W=32, C=256. 8 tasks (sample x orientation), grid L=992 each.
// Pipeline (6 dispatches):
//   k_stage:    Mh=f16(a*b), ABt (transposed f16 a|b), per-pixel sq norms
//   k_gram:     S = Mh Mh^T (MFMA f16 -> B0), 64x64 tiles; u==0 also inv
//   k_softmax9: G = 9-pt band(S) -> MAX-FREE softmax -> Ph (B0->B1)
//               (|logit|<=10 by Cauchy-Schwarz: exp fp32-safe, no max pass)
//   k_band9p:   Wh = 9-pt band(Ph) (B1->B0)
//   k_recon:    Y(f16) = Wh @ ABt^T (MFMA f16), 64x64 tiles
//   k_combine:  seam average -> out
// R8 lesson: symmetric-gram mirror + wave-per-row restructure regressed;
// this is R7 (best known) plus ONLY the max-free softmax deletion.

typedef _Float16 half8 __attribute__((ext_vector_type(8)));
typedef _Float16 half8u __attribute__((ext_vector_type(8), aligned(4)));
typedef _Float16 half4h __attribute__((ext_vector_type(4)));
typedef _Float16 half4u __attribute__((ext_vector_type(4), aligned(8)));
typedef float floatx4 __attribute__((ext_vector_type(4)));

constexpr int NL = 992, NC = 256, NC2 = 512;
constexpr int NLL = NL * NL;
// float-granular per-task offsets. B0/B1 last: +-66KB stencil over/under-
// reads stay inside d_ws (ws is 256MB, we use 47.8MB).
constexpr int OFF_ABT = 0;                      // f16 [512][992]
constexpr int OFF_MH  = OFF_ABT + NL * NC2 / 2; // f16 [992][256]
constexpr int OFF_SA  = OFF_MH + NL * NC / 2;
constexpr int OFF_SB  = OFF_SA + 1024;
constexpr int OFF_INV = OFF_SA + 2048;          // 1024 slots
constexpr int OFF_Y   = OFF_SA + 3072;          // f16 [992][512]
constexpr int OFF_B0  = OFF_Y + NL * NC2 / 2;   // f16 LxL: S, later Wh
constexpr int OFF_B1  = OFF_B0 + NLL / 2;       // f16 LxL: Ph
constexpr int TSTRIDE = OFF_B1 + NLL / 2;       // 1,495,040 f -> 47.8 MB

__device__ __forceinline__ void gload16(const void* g, void* l) {
    __builtin_amdgcn_global_load_lds(
        (const __attribute__((address_space(1))) unsigned int*)g,
        (__attribute__((address_space(3))) unsigned int*)(unsigned long)(uintptr_t)l,
        16, 0, 0);
}

// ------- K1: one x-pass -> Mh, ABt (both halves), per-pixel sq norms -------
__global__ __launch_bounds__(256) void k_stage(const float* __restrict__ x,
                                               float* __restrict__ ws) {
    const int t = blockIdx.x & 7;
    const int l0 = (blockIdx.x >> 3) * 32;   // 31 l-blocks
    const int s = t >> 1, o = t & 1;
    float* wst = ws + (size_t)t * TSTRIDE;
    _Float16* __restrict__ ABt = (_Float16*)(wst + OFF_ABT);
    _Float16* __restrict__ Mh = (_Float16*)(wst + OFF_MH);
    __shared__ float Ta[32 * 33], Tb[32 * 33];
    const int tid = threadIdx.x;
    const int li = tid >> 3, cq = tid & 7;
    const int l = l0 + li;
    int aoff, boff;
    if (o == 0) {  // lr grid (31,32): a=x[s,lh,lw], b=x[s,lh+1,lw]
        const int lh = l >> 5, lw = l & 31;
        aoff = ((s * 32 + lh) * 32 + lw) * NC;
        boff = aoff + 32 * NC;
    } else {       // tb grid (32,31): a=x[s,lh,lw+1], b=x[s,lh,lw]
        const int lh = l / 31, lw = l - lh * 31;
        boff = ((s * 32 + lh) * 32 + lw) * NC;
        aoff = boff + NC;
    }
    float sa = 0.0f, sb = 0.0f;
    for (int cc = 0; cc < 8; ++cc) {
        const int c0 = cc * 32;
        const float4 a4 = *(const float4*)&x[aoff + c0 + cq * 4];
        const float4 b4 = *(const float4*)&x[boff + c0 + cq * 4];
        half4h m;
        m[0] = (_Float16)(a4.x * b4.x); m[1] = (_Float16)(a4.y * b4.y);
        m[2] = (_Float16)(a4.z * b4.z); m[3] = (_Float16)(a4.w * b4.w);
        *(half4u*)&Mh[l * NC + c0 + cq * 4] = m;
        sa += a4.x * a4.x + a4.y * a4.y + a4.z * a4.z + a4.w * a4.w;
        sb += b4.x * b4.x + b4.y * b4.y + b4.z * b4.z + b4.w * b4.w;
        __syncthreads();   // guard previous iteration's LDS reads
        Ta[(cq * 4 + 0) * 33 + li] = a4.x; Tb[(cq * 4 + 0) * 33 + li] = b4.x;
        Ta[(cq * 4 + 1) * 33 + li] = a4.y; Tb[(cq * 4 + 1) * 33 + li] = b4.y;
        Ta[(cq * 4 + 2) * 33 + li] = a4.z; Tb[(cq * 4 + 2) * 33 + li] = b4.z;
        Ta[(cq * 4 + 3) * 33 + li] = a4.w; Tb[(cq * 4 + 3) * 33 + li] = b4.w;
        __syncthreads();
        const int ci = li, lq = cq;
        half4h ha, hb;
#pragma unroll
        for (int j = 0; j < 4; ++j) {
            ha[j] = (_Float16)Ta[ci * 33 + lq * 4 + j];
            hb[j] = (_Float16)Tb[ci * 33 + lq * 4 + j];
        }
        *(half4u*)&ABt[(c0 + ci) * NL + l0 + lq * 4] = ha;
        *(half4u*)&ABt[(NC + c0 + ci) * NL + l0 + lq * 4] = hb;
    }
#pragma unroll
    for (int off = 4; off > 0; off >>= 1) {
        sa += __shfl_down(sa, off, 8);
        sb += __shfl_down(sb, off, 8);
    }
    if (cq == 0) {
        wst[OFF_SA + l] = sa;
        wst[OFF_SB + l] = sb;
    }
}

// -------- K2: S = Mh Mh^T, 64x64 tile, BK=64; u==0 blocks also do inv -------
__global__ __launch_bounds__(256) void k_gram(float* __restrict__ ws) {
    const int t = blockIdx.x & 7;
    const int u = blockIdx.x >> 3;    // 0..255 = 16 iy x 16 jx
    const int i0 = (u >> 4) * 64, j0 = (u & 15) * 64;
    float* wst = ws + (size_t)t * TSTRIDE;
    const _Float16* __restrict__ M = (const _Float16*)(wst + OFF_MH);
    _Float16* __restrict__ S = (_Float16*)(wst + OFF_B0);
    const int tid = threadIdx.x;

    if (u == 0) {  // fused inv: 3x3 box sums of sq norms -> 1/(max*max)
        const int o = t & 1;
        const int Hp = o ? 32 : 31, Wp = o ? 31 : 32;
#pragma unroll
        for (int q = 0; q < 4; ++q) {
            const int l = tid + q * 256;
            if (l < NL) {
                const int h = l / Wp, w = l - h * Wp;
                float na2 = 0.0f, nb2 = 0.0f;
#pragma unroll
                for (int dh = -1; dh <= 1; ++dh)
#pragma unroll
                    for (int dw = -1; dw <= 1; ++dw) {
                        const int hh = h + dh, ww = w + dw;
                        if ((unsigned)hh < (unsigned)Hp && (unsigned)ww < (unsigned)Wp) {
                            const int ll = hh * Wp + ww;
                            na2 += wst[OFF_SA + ll];
                            nb2 += wst[OFF_SB + ll];
                        }
                    }
                const float na = fmaxf(sqrtf(na2), 1e-4f);
                const float nb = fmaxf(sqrtf(nb2), 1e-4f);
                wst[OFF_INV + l] = 1.0f / (na * nb);
            }
        }
    }

    __shared__ __align__(16) _Float16 As[64 * 64];
    __shared__ __align__(16) _Float16 Bs[64 * 64];
    const int wave = tid >> 6, lane = tid & 63;
    const int wm = wave & 1, wn = wave >> 1;
    const int l15 = lane & 15, quad = lane >> 4;
    floatx4 acc[2][2] = {};
    for (int k0 = 0; k0 < NC; k0 += 64) {   // 4 iters
        __syncthreads();
#pragma unroll
        for (int rr = 0; rr < 2; ++rr) {
            const int slot = tid + rr * 256;
            const int row = slot >> 3, cg = (slot & 7) * 8;
            if (i0 + row < NL) gload16(&M[(i0 + row) * NC + k0 + cg], &As[row * 64 + cg]);
            if (j0 + row < NL) gload16(&M[(j0 + row) * NC + k0 + cg], &Bs[row * 64 + cg]);
        }
        __syncthreads();
#pragma unroll
        for (int kk = 0; kk < 2; ++kk) {
            half8 a[2], b[2];
#pragma unroll
            for (int mt = 0; mt < 2; ++mt) a[mt] = *(const half8*)&As[(wm * 32 + mt * 16 + l15) * 64 + kk * 32 + quad * 8];
#pragma unroll
            for (int nt = 0; nt < 2; ++nt) b[nt] = *(const half8*)&Bs[(wn * 32 + nt * 16 + l15) * 64 + kk * 32 + quad * 8];
#pragma unroll
            for (int mt = 0; mt < 2; ++mt)
#pragma unroll
                for (int nt = 0; nt < 2; ++nt)
                    acc[mt][nt] = __builtin_amdgcn_mfma_f32_16x16x32_f16(a[mt], b[nt], acc[mt][nt], 0, 0, 0);
        }
    }
#pragma unroll
    for (int mt = 0; mt < 2; ++mt)
#pragma unroll
        for (int nt = 0; nt < 2; ++nt)
#pragma unroll
            for (int r = 0; r < 4; ++r) {
                const int row = i0 + wm * 32 + mt * 16 + quad * 4 + r;
                const int col = j0 + wn * 32 + nt * 16 + l15;
                if (row < NL && col < NL) S[row * NL + col] = (_Float16)acc[mt][nt][r];
            }
}

// -- K3: G = 9-pt band(S) -> MAX-FREE softmax -> Ph, B0 -> B1 --
// |logit| = |10*G*inv1*inv2| <= 10 (Cauchy-Schwarz), exp fp32-safe w/o max.
template<int WP, int HP>
__device__ __forceinline__ void softmax9_body(float* __restrict__ wst,
                                              const int l1, const int tid) {
    const _Float16* __restrict__ S = (const _Float16*)(wst + OFF_B0);
    const float* __restrict__ inv = wst + OFF_INV;
    _Float16* __restrict__ Ph = (_Float16*)(wst + OFF_B1);
    const int c0 = tid * 4;
    const int h1 = l1 / WP, w1 = l1 % WP;
    float e[4] = {0.f, 0.f, 0.f, 0.f};
    float sum = 0.0f;
    if (tid < 248) {
        int hc[4], wc[4];
#pragma unroll
        for (int j = 0; j < 4; ++j) { hc[j] = (c0 + j) / WP; wc[j] = (c0 + j) % WP; }
        float g[4] = {0.f, 0.f, 0.f, 0.f};
        const _Float16* base = S + l1 * NL + c0;
#pragma unroll
        for (int dh = -1; dh <= 1; ++dh) {
            const bool oh1 = (unsigned)(h1 + dh) < (unsigned)HP;
#pragma unroll
            for (int dw = -1; dw <= 1; ++dw) {
                const int sh = dh * WP + dw;     // compile-time after unroll
                const int par = sh & 1;
                const bool ok1 = oh1 && (unsigned)(w1 + dw) < (unsigned)WP;
                const half8u v = *(const half8u*)(base + sh * (NL + 1) - par);
#pragma unroll
                for (int j = 0; j < 4; ++j) {
                    const bool ok = ok1 && (unsigned)(hc[j] + dh) < (unsigned)HP &&
                                           (unsigned)(wc[j] + dw) < (unsigned)WP;
                    if (ok) g[j] += (float)v[j + par];
                }
            }
        }
        const float inv1 = inv[l1] * 10.0f;
#pragma unroll
        for (int j = 0; j < 4; ++j) {
            e[j] = __expf(g[j] * inv1 * inv[c0 + j]);
            sum += e[j];
        }
    }
    __shared__ float red[4];
    const int wave = tid >> 6, lane = tid & 63;
#pragma unroll
    for (int off = 32; off > 0; off >>= 1) sum += __shfl_down(sum, off);
    if (lane == 0) red[wave] = sum;
    __syncthreads();
    sum = red[0] + red[1] + red[2] + red[3];
    const float rs = 1.0f / sum;
    if (tid < 248) {
        half4h o;
#pragma unroll
        for (int j = 0; j < 4; ++j) o[j] = (_Float16)(e[j] * rs);
        *(half4u*)(Ph + l1 * NL + c0) = o;
    }
}

__global__ __launch_bounds__(256) void k_softmax9(float* __restrict__ ws) {
    const int t = blockIdx.x & 7;
    const int l1 = blockIdx.x >> 3;
    float* wst = ws + (size_t)t * TSTRIDE;
    if (t & 1) softmax9_body<31, 32>(wst, l1, threadIdx.x);
    else       softmax9_body<32, 31>(wst, l1, threadIdx.x);
}

// ---------------- K4: Wh = 9-pt band(Ph), B1 -> B0 ----------------
template<int WP, int HP>
__device__ __forceinline__ void band9p_body(float* __restrict__ wst,
                                            const int m, const int tid) {
    if (tid >= 248) return;
    const _Float16* __restrict__ P = (const _Float16*)(wst + OFF_B1);
    _Float16* __restrict__ W = (_Float16*)(wst + OFF_B0);
    const int c0 = tid * 4;
    const int hm = m / WP, wm = m % WP;
    int hc[4], wc[4];
#pragma unroll
    for (int j = 0; j < 4; ++j) { hc[j] = (c0 + j) / WP; wc[j] = (c0 + j) % WP; }
    float acc[4] = {0.f, 0.f, 0.f, 0.f};
    const _Float16* base = P + m * NL + c0;
#pragma unroll
    for (int dh = -1; dh <= 1; ++dh) {
        const bool oh1 = (unsigned)(hm + dh) < (unsigned)HP;
#pragma unroll
        for (int dw = -1; dw <= 1; ++dw) {
            const int sh = dh * WP + dw;
            const int par = sh & 1;
            const bool ok1 = oh1 && (unsigned)(wm + dw) < (unsigned)WP;
            const half8u v = *(const half8u*)(base + sh * (NL + 1) - par);
#pragma unroll
            for (int j = 0; j < 4; ++j) {
                const bool ok = ok1 && (unsigned)(hc[j] + dh) < (unsigned)HP &&
                                       (unsigned)(wc[j] + dw) < (unsigned)WP;
                if (ok) acc[j] += (float)v[j + par];
            }
        }
    }
    half4h o;
#pragma unroll
    for (int j = 0; j < 4; ++j) o[j] = (_Float16)acc[j];
    *(half4u*)(W + m * NL + c0) = o;
}

__global__ __launch_bounds__(256) void k_band9p(float* __restrict__ ws) {
    const int t = blockIdx.x & 7;
    const int m = blockIdx.x >> 3;
    float* wst = ws + (size_t)t * TSTRIDE;
    if (t & 1) band9p_body<31, 32>(wst, m, threadIdx.x);
    else       band9p_body<32, 31>(wst, m, threadIdx.x);
}

// -------- K5: Y(f16) = Wh @ ABt^T, 64x64 tile, BK=32, 31 exact iters -------
__global__ __launch_bounds__(256) void k_recon(float* __restrict__ ws) {
    const int t = blockIdx.x & 7;
    const int u = blockIdx.x >> 3;    // 0..127 = 16 iy x 8 jx
    const int i0 = (u >> 3) * 64, j0 = (u & 7) * 64;
    float* wst = ws + (size_t)t * TSTRIDE;
    const _Float16* __restrict__ Wm = (const _Float16*)(wst + OFF_B0);
    const _Float16* __restrict__ ABt = (const _Float16*)(wst + OFF_ABT);
    _Float16* __restrict__ Y = (_Float16*)(wst + OFF_Y);
    __shared__ __align__(16) _Float16 As[64 * 32];
    __shared__ __align__(16) _Float16 Bs[64 * 32];
    const int tid = threadIdx.x;
    const int wave = tid >> 6, lane = tid & 63;
    const int wm = wave & 1, wn = wave >> 1;
    const int l15 = lane & 15, quad = lane >> 4;
    floatx4 acc[2][2] = {};
    const int row = tid >> 2, cg = (tid & 3) * 8;
    for (int k0 = 0; k0 < NL; k0 += 32) {   // 31 exact iterations
        __syncthreads();
        if (i0 + row < NL) gload16(&Wm[(i0 + row) * NL + k0 + cg], &As[row * 32 + cg]);
        gload16(&ABt[(j0 + row) * NL + k0 + cg], &Bs[row * 32 + cg]);
        __syncthreads();
        half8 a[2], b[2];
#pragma unroll
        for (int mt = 0; mt < 2; ++mt) a[mt] = *(const half8*)&As[(wm * 32 + mt * 16 + l15) * 32 + quad * 8];
#pragma unroll
        for (int nt = 0; nt < 2; ++nt) b[nt] = *(const half8*)&Bs[(wn * 32 + nt * 16 + l15) * 32 + quad * 8];
#pragma unroll
        for (int mt = 0; mt < 2; ++mt)
#pragma unroll
            for (int nt = 0; nt < 2; ++nt)
                acc[mt][nt] = __builtin_amdgcn_mfma_f32_16x16x32_f16(a[mt], b[nt], acc[mt][nt], 0, 0, 0);
    }
#pragma unroll
    for (int mt = 0; mt < 2; ++mt)
#pragma unroll
        for (int nt = 0; nt < 2; ++nt)
#pragma unroll
            for (int r = 0; r < 4; ++r) {
                const int rw = i0 + wm * 32 + mt * 16 + quad * 4 + r;
                const int col = j0 + wn * 32 + nt * 16 + l15;
                if (rw < NL) Y[rw * NC2 + col] = (_Float16)acc[mt][nt][r];
            }
}

// ---------------- K6: seam combine -> out ----------------
__global__ __launch_bounds__(256) void k_combine(float* __restrict__ out,
                                                 const float* __restrict__ ws) {
    const int idx = blockIdx.x;          // s*1024 + h*32 + w
    const int s = idx >> 10;
    const int hw = idx & 1023;
    const int h = hw >> 5, w = hw & 31;
    const int c = threadIdx.x;
    const _Float16* Ylr = (const _Float16*)(ws + (size_t)(2 * s) * TSTRIDE + OFF_Y);
    const _Float16* Ytb = (const _Float16*)(ws + (size_t)(2 * s + 1) * TSTRIDE + OFF_Y);
    float v = 0.0f;
    if (h < 31) v += (float)Ylr[(h * 32 + w) * NC2 + NC + c] * (h == 0 ? 1.0f : 0.5f);
    if (h >= 1) v += (float)Ylr[((h - 1) * 32 + w) * NC2 + c] * (h == 31 ? 1.0f : 0.5f);
    if (w < 31) v += (float)Ytb[(h * 31 + w) * NC2 + c] * (w == 0 ? 1.0f : 0.5f);
    if (w >= 1) v += (float)Ytb[(h * 31 + (w - 1)) * NC2 + NC + c] * (w == 31 ? 1.0f : 0.5f);
    out[(size_t)idx * NC + c] = v * 0.5f;
}

extern "C" void kernel_launch(void* const* d_in, const int* in_sizes, int n_in,
                              void* d_out, int out_size, void* d_ws, size_t ws_size,
                              hipStream_t stream) {
    const float* x = (const float*)d_in[0];
    float* out = (float*)d_out;
    float* ws = (float*)d_ws;    // 8*TSTRIDE*4 = 47.8 MB used

    hipLaunchKernelGGL(k_stage,    dim3(8 * 31),  dim3(256), 0, stream, x, ws);
    hipLaunchKernelGGL(k_gram,     dim3(8 * 256), dim3(256), 0, stream, ws);
    hipLaunchKernelGGL(k_softmax9, dim3(8 * NL),  dim3(256), 0, stream, ws);
    hipLaunchKernelGGL(k_band9p,   dim3(8 * NL),  dim3(256), 0, stream, ws);
    hipLaunchKernelGGL(k_recon,    dim3(8 * 128), dim3(256), 0, stream, ws);
    hipLaunchKernelGGL(k_combine,  dim3(4096),    dim3(256), 0, stream, out, ws);
}